// Round 5
// baseline (862.468 us; speedup 1.0000x reference)
//
#include <hip/hip_runtime.h>
#include <hip/hip_bf16.h>
#include <stdint.h>

#define TT 2048
#define BB 8
#define DD 1024
#define FF 2048   // 4*H*N
#define HN 512
#define KB_CNT 32         // DD/32 k-blocks
#define ROWB 128          // bytes per (row, k-block): 8 slots * 16B
#define MSTRIDE 4096      // bytes per row in split layout = KB_CNT*ROWB
#define PF 8              // recurrence pipeline depth (8 steps * 4 loads = 32 in flight)

typedef float f32x4 __attribute__((ext_vector_type(4)));
typedef float f32x2 __attribute__((ext_vector_type(2)));
typedef _Float16 h8_t __attribute__((ext_vector_type(8)));

// ---------- fast math helpers ----------
__device__ __forceinline__ float fexp2(float x){ return __builtin_amdgcn_exp2f(x); }
__device__ __forceinline__ float frcp(float x){ return __builtin_amdgcn_rcpf(x); }
__device__ __forceinline__ float fsqrt_(float x){ return __builtin_amdgcn_sqrtf(x); }
__device__ __forceinline__ float fast_sigmoid(float x){
    return frcp(1.0f + fexp2(-1.44269504f * x));
}

// DPP butterfly add (old=0, bound_ctrl -> fetch-0; all fetches within 16-lane row)
template<int CTRL>
__device__ __forceinline__ float dppadd(float v){
    int x = __builtin_amdgcn_update_dpp(0, __float_as_int(v), CTRL, 0xf, 0xf, true);
    return v + __int_as_float(x);
}
// sum over 16-lane group (row_mirror = xor8 within a 16-lane DPP row)
__device__ __forceinline__ float reduce16(float v){
    v = dppadd<0xB1>(v);   // quad_perm [1,0,3,2]  : + lane^1
    v = dppadd<0x4E>(v);   // quad_perm [2,3,0,1]  : + lane^2
    v = dppadd<0x141>(v);  // row_half_mirror      : + lane^4 (within 8)
    v = dppadd<0x140>(v);  // row_mirror           : + lane^8 (within 16)
    return v;
}

// ---------- concat the 4 projection weights into [2048,1024] ----------
__global__ __launch_bounds__(256)
void concat4(const float* __restrict__ s0, const float* __restrict__ s1,
             const float* __restrict__ s2, const float* __restrict__ s3,
             float* __restrict__ dst)
{
    size_t i = (size_t)blockIdx.x * 256 + threadIdx.x;
    const size_t q = (size_t)HN * DD / 4;
    const float* s = (i < q) ? s0 : (i < 2*q) ? s1 : (i < 3*q) ? s2 : s3;
    size_t off = i & (q - 1);
    ((float4*)dst)[i] = ((const float4*)s)[off];
}

// ---------- fp32 tiled GEMM (only for the tiny Weff product) ----------
__global__ __launch_bounds__(256)
void gemm_f32(const float* __restrict__ A, const float* __restrict__ B,
              float* __restrict__ C, int M, int N, int K)
{
    __shared__ __align__(16) float As[16][132];
    __shared__ __align__(16) float Bs[16][144];
    const int tid = threadIdx.x;
    const int tx = tid & 15, ty = tid >> 4;
    const int n0 = blockIdx.x * 128, m0 = blockIdx.y * 128;
    float acc[8][8] = {};
    for (int k0 = 0; k0 < K; k0 += 16) {
        #pragma unroll
        for (int rr = 0; rr < 2; ++rr) {
            int idx = tid + rr * 256;
            int row = idx >> 2, c4 = (idx & 3) << 2;
            float4 v = *(const float4*)&A[(size_t)(m0 + row) * K + k0 + c4];
            As[c4+0][row] = v.x; As[c4+1][row] = v.y;
            As[c4+2][row] = v.z; As[c4+3][row] = v.w;
        }
        #pragma unroll
        for (int rr = 0; rr < 2; ++rr) {
            int idx = tid + rr * 256;
            int kk = idx >> 5, c = idx & 31;
            float4 v = *(const float4*)&B[(size_t)(k0 + kk) * N + n0 + (c << 2)];
            int p = c + (c >> 3);
            *(float4*)&Bs[kk][p << 2] = v;
        }
        __syncthreads();
        #pragma unroll
        for (int kk = 0; kk < 16; ++kk) {
            float a[8], b[8];
            *(float4*)&a[0] = *(const float4*)&As[kk][ty * 8];
            *(float4*)&a[4] = *(const float4*)&As[kk][ty * 8 + 4];
            int c = tx * 2, p = c + (c >> 3);
            *(float4*)&b[0] = *(const float4*)&Bs[kk][p << 2];
            *(float4*)&b[4] = *(const float4*)&Bs[kk][(p + 1) << 2];
            #pragma unroll
            for (int i = 0; i < 8; ++i)
                #pragma unroll
                for (int j = 0; j < 8; ++j)
                    acc[i][j] += a[i] * b[j];
        }
        __syncthreads();
    }
    #pragma unroll
    for (int ii = 0; ii < 8; ++ii) {
        int m = m0 + ty * 8 + ii;
        float* crow = &C[(size_t)m * N + n0 + tx * 8];
        #pragma unroll
        for (int jj = 0; jj < 2; ++jj) {
            float4 v;
            v.x = acc[ii][jj*4+0]; v.y = acc[ii][jj*4+1];
            v.z = acc[ii][jj*4+2]; v.w = acc[ii][jj*4+3];
            *(float4*)&crow[jj * 4] = v;
        }
    }
}

// ---------- split fp32 -> (hi,lo) fp16, pre-swizzled layout ----------
__device__ __forceinline__ void split8(const float* f, int4& hi, int4& lo){
    union { _Float16 h[8]; int4 i; } a, c;
    #pragma unroll
    for (int u = 0; u < 8; ++u) {
        _Float16 h = (_Float16)f[u];
        a.h[u] = h;
        c.h[u] = (_Float16)(f[u] - (float)h);
    }
    hi = a.i; lo = c.i;
}

__global__ __launch_bounds__(256)
void wconv(const float* __restrict__ W, char* __restrict__ out)
{
    int gid = blockIdx.x * 256 + threadIdx.x;
    int n  = gid >> 6;
    int kh = gid & 63;
    const float* src = W + (size_t)n * DD + kh * 16;
    float f[16];
    *(float4*)&f[0]  = *(const float4*)(src + 0);
    *(float4*)&f[4]  = *(const float4*)(src + 4);
    *(float4*)&f[8]  = *(const float4*)(src + 8);
    *(float4*)&f[12] = *(const float4*)(src + 12);
    int4 hi0, hi1, lo0, lo1;
    split8(&f[0], hi0, lo0);
    split8(&f[8], hi1, lo1);
    int kb = kh >> 1, c0 = (kh & 1) * 2, rs = n & 7;
    char* dst = out + (size_t)n * MSTRIDE + kb * ROWB;
    *(int4*)(dst + (((c0+0) ^ rs) * 16)) = hi0;
    *(int4*)(dst + (((c0+1) ^ rs) * 16)) = hi1;
    *(int4*)(dst + (((c0+4) ^ rs) * 16)) = lo0;
    *(int4*)(dst + (((c0+5) ^ rs) * 16)) = lo1;
}

// ---------- fp16x2-split MFMA GEMM (unchanged) ----------
__global__ __launch_bounds__(256)
void gemm_mfma(const float* __restrict__ A, const char* __restrict__ Wsp,
               float* __restrict__ C, const float* __restrict__ bias)
{
    __shared__ char lds[32768];
    char* Asb = lds;
    char* Bsb = lds + 16384;

    const int tid  = threadIdx.x;
    const int wave = tid >> 6, lane = tid & 63;
    const int wm = wave >> 1, wn = wave & 1;
    const int nt = blockIdx.x & 15, mt = blockIdx.x >> 4;
    const int m0 = mt * 128, n0 = nt * 128;

    f32x4 acc[4][4] = {};

    const int ar = tid >> 1, akh = tid & 1, ars = ar & 7, ac0 = akh * 2;
    const float* asrc = A + (size_t)(m0 + ar) * DD + akh * 16;
    char* awr = Asb + ar * ROWB;

    const char* bsrc_base = Wsp + (size_t)n0 * MSTRIDE;

    const int fl = lane & 15, fh = lane >> 4;
    const int shi = (fh ^ (fl & 7)) * 16;
    const int slo = ((fh + 4) ^ (fl & 7)) * 16;
    const int frow = fl * ROWB;

    for (int ks = 0; ks < KB_CNT; ++ks) {
        #pragma unroll
        for (int gg = 0; gg < 4; ++gg) {
            int g = wave * 4 + gg;
            const char* src = bsrc_base + (size_t)(g * 8 + (lane >> 3)) * MSTRIDE
                              + ks * ROWB + (lane & 7) * 16;
            __builtin_amdgcn_global_load_lds(
                (const __attribute__((address_space(1))) uint32_t*)src,
                (__attribute__((address_space(3))) uint32_t*)(Bsb + g * 1024),
                16, 0, 0);
        }
        {
            const float* ap = asrc + ks * 32;
            float f[16];
            *(float4*)&f[0]  = *(const float4*)(ap + 0);
            *(float4*)&f[4]  = *(const float4*)(ap + 4);
            *(float4*)&f[8]  = *(const float4*)(ap + 8);
            *(float4*)&f[12] = *(const float4*)(ap + 12);
            int4 hi0, hi1, lo0, lo1;
            split8(&f[0], hi0, lo0);
            split8(&f[8], hi1, lo1);
            *(int4*)(awr + (((ac0+0) ^ ars) * 16)) = hi0;
            *(int4*)(awr + (((ac0+1) ^ ars) * 16)) = hi1;
            *(int4*)(awr + (((ac0+4) ^ ars) * 16)) = lo0;
            *(int4*)(awr + (((ac0+5) ^ ars) * 16)) = lo1;
        }
        __syncthreads();

        union { int4 i; h8_t h; } ah[4], al[4], bh[4], bl[4];
        #pragma unroll
        for (int fm = 0; fm < 4; ++fm) {
            const char* base = Asb + (wm * 64 + fm * 16) * ROWB + frow;
            ah[fm].i = *(const int4*)(base + shi);
            al[fm].i = *(const int4*)(base + slo);
        }
        #pragma unroll
        for (int fn = 0; fn < 4; ++fn) {
            const char* base = Bsb + (wn * 64 + fn * 16) * ROWB + frow;
            bh[fn].i = *(const int4*)(base + shi);
            bl[fn].i = *(const int4*)(base + slo);
        }
        #pragma unroll
        for (int fm = 0; fm < 4; ++fm)
            #pragma unroll
            for (int fn = 0; fn < 4; ++fn) {
                acc[fm][fn] = __builtin_amdgcn_mfma_f32_16x16x32_f16(ah[fm].h, bh[fn].h, acc[fm][fn], 0, 0, 0);
                acc[fm][fn] = __builtin_amdgcn_mfma_f32_16x16x32_f16(ah[fm].h, bl[fn].h, acc[fm][fn], 0, 0, 0);
                acc[fm][fn] = __builtin_amdgcn_mfma_f32_16x16x32_f16(al[fm].h, bh[fn].h, acc[fm][fn], 0, 0, 0);
            }
        __syncthreads();
    }

    const bool isbeta = (nt >= 12);
    #pragma unroll
    for (int fm = 0; fm < 4; ++fm) {
        int rbase = m0 + wm * 64 + fm * 16 + fh * 4;
        #pragma unroll
        for (int fn = 0; fn < 4; ++fn) {
            int col = n0 + wn * 64 + fn * 16 + fl;
            float bb = isbeta ? bias[col - 3 * HN] : 0.0f;
            #pragma unroll
            for (int reg = 0; reg < 4; ++reg) {
                float v = acc[fm][fn][reg];
                if (isbeta) v = fast_sigmoid(v + bb);
                C[(size_t)(rbase + reg) * FF + col] = v;
            }
        }
    }
}

// ---------- sequential recurrence ----------
// 512 blocks x 128 threads (2 waves) = 1024 waves -> 1 wave on EVERY SIMD.
// 16 lanes per state row (jl = lane&15 owns j = 2jl, 2jl+1); wave covers 4
// rows. reduce16 = 4 DPP butterfly adds. Carried chain per step:
// fma(dot) -> 4 DPP -> fma(g2) -> fma(arg) -> exp2 -> add -> rcp -> fma.
// Constants c0 = 2.885*rn*v, c1 = -2.885*rn^2, bS = 2.885*beta*S for step t+1
// are computed off-chain during step t. Flat-form asm loads (proven R3 path),
// PF=8 rotating slots, counted s_waitcnt vmcnt(24), data-threaded "+v".
__global__ __launch_bounds__(128)
void recur(const float* __restrict__ proj, const float* __restrict__ S0,
           float* __restrict__ out, float* __restrict__ Sfin)
{
    const int tid = threadIdx.x;
    const int gr  = blockIdx.x * 8 + (tid >> 4);   // global state row 0..4095
    const int bh  = gr >> 5;                        // chain 0..127
    const int i   = gr & 31;                        // row within state
    const int b   = bh >> 4, h = bh & 15;
    const int jl  = tid & 15;                       // owns j = 2jl, 2jl+1

    float S0v, S1v;
    {
        const float* s0p = S0 + (size_t)bh * 1024 + i * 32 + 2 * jl;
        S0v = s0p[0]; S1v = s0p[1];
    }

    const size_t rowstep = (size_t)BB * FF;              // 16384 floats per t
    const float* pk = proj + (size_t)b * FF + h * 32 + 2 * jl;
    const float* pq = pk + 2 * HN;
    const float* pv = proj + (size_t)b * FF + HN + h * 32 + i;
    const float* pb = pv + 2 * HN;

    f32x2 K[PF], Q[PF];
    float V[PF], Bt[PF];

    // prologue: issue PF steps (4 loads each, order k,q,v,b)
    #pragma unroll
    for (int p = 0; p < PF; ++p) {
        asm volatile("global_load_dwordx2 %0, %1, off" : "=v"(K[p])  : "v"(pk + p * rowstep));
        asm volatile("global_load_dwordx2 %0, %1, off" : "=v"(Q[p])  : "v"(pq + p * rowstep));
        asm volatile("global_load_dword %0, %1, off"   : "=v"(V[p])  : "v"(pv + p * rowstep));
        asm volatile("global_load_dword %0, %1, off"   : "=v"(Bt[p]) : "v"(pb + p * rowstep));
    }

    // prime step-0 constants (wait slot 0: 32 outstanding -> 28)
    asm volatile("s_waitcnt vmcnt(28)"
        : "+v"(K[0]), "+v"(Q[0]), "+v"(V[0]), "+v"(Bt[0]));
    float c0_cur, c1_cur, bS0, bS1;
    {
        float s2 = K[0][0] * K[0][0];
        s2 = __builtin_fmaf(K[0][1], K[0][1], s2);
        s2 = reduce16(s2);
        float rn  = frcp(fsqrt_(s2) + 1e-6f);
        c1_cur = -2.88539008f * (rn * rn);
        c0_cur = (2.88539008f * V[0]) * rn;
        float b2 = 2.88539008f * Bt[0];
        bS0 = b2 * S0v; bS1 = b2 * S1v;
    }

    float* pout = out + (size_t)b * HN + h * 32 + i;   // stored when jl==0
    size_t off8 = (size_t)PF * rowstep;                 // float offset of step t+PF

    for (int t0 = 0; t0 < TT; t0 += PF) {
        #pragma unroll
        for (int p = 0; p < PF; ++p) {
            const int t = t0 + p;
            const int pn = (p + 1) & (PF - 1);
            // guarantees steps t (slot p, waited last iter) and t+1 (slot pn)
            // are complete; data-threading orders consumers after the wait.
            asm volatile("s_waitcnt vmcnt(24)"
                : "+v"(K[pn]), "+v"(Q[pn]), "+v"(V[pn]), "+v"(Bt[pn]));

            // ---- carried chain ----
            f32x2 k4 = K[p];
            float rr = S0v * k4[0];
            rr = __builtin_fmaf(S1v, k4[1], rr);
            rr = reduce16(rr);
            float g2 = __builtin_fmaf(rr, c1_cur, c0_cur);   // 2.885*delta*rn
            float a0 = __builtin_fmaf(g2, k4[0], bS0);
            float a1 = __builtin_fmaf(g2, k4[1], bS1);
            float e0 = fexp2(a0), e1 = fexp2(a1);
            float r0 = frcp(e0 + 1.0f), r1 = frcp(e1 + 1.0f);
            S0v = __builtin_fmaf(-2.0f, r0, 1.0f);
            S1v = __builtin_fmaf(-2.0f, r1, 1.0f);

            // ---- output ----
            f32x2 q4 = Q[p];
            float sq = S0v * q4[0];
            sq = __builtin_fmaf(S1v, q4[1], sq);
            sq = reduce16(sq);
            if (jl == 0) {
                float sg = fast_sigmoid(sq);
                *pout = sq * sq * sg;
            }
            pout += BB * HN;

            // ---- precompute constants for step t+1 (off-chain) ----
            {
                f32x2 kn = K[pn];
                float s2 = kn[0] * kn[0];
                s2 = __builtin_fmaf(kn[1], kn[1], s2);
                s2 = reduce16(s2);
                float rn  = frcp(fsqrt_(s2) + 1e-6f);
                c1_cur = -2.88539008f * (rn * rn);
                c0_cur = (2.88539008f * V[pn]) * rn;
                float b2 = 2.88539008f * Bt[pn];
                bS0 = b2 * S0v; bS1 = b2 * S1v;
            }

            // ---- reissue slot p for step t+PF (clamped to last row) ----
            asm volatile("global_load_dwordx2 %0, %1, off" : "=v"(K[p])  : "v"(pk + off8));
            asm volatile("global_load_dwordx2 %0, %1, off" : "=v"(Q[p])  : "v"(pq + off8));
            asm volatile("global_load_dword %0, %1, off"   : "=v"(V[p])  : "v"(pv + off8));
            asm volatile("global_load_dword %0, %1, off"   : "=v"(Bt[p]) : "v"(pb + off8));
            if (t + PF < TT - 1) off8 += rowstep;
        }
    }

    {
        float* sf = Sfin + (size_t)bh * 1024 + i * 32 + 2 * jl;
        sf[0] = S0v; sf[1] = S1v;
    }
}

extern "C" void kernel_launch(void* const* d_in, const int* in_sizes, int n_in,
                              void* d_out, int out_size, void* d_ws, size_t ws_size,
                              hipStream_t stream) {
    const float* x      = (const float*)d_in[0];
    const float* S0     = (const float*)d_in[1];
    const float* W_in   = (const float*)d_in[2];
    const float* W_k    = (const float*)d_in[3];
    const float* W_v    = (const float*)d_in[4];
    const float* W_q    = (const float*)d_in[5];
    const float* W_beta = (const float*)d_in[6];
    const float* b_beta = (const float*)d_in[7];

    float* ws    = (float*)d_ws;
    float* proj  = ws;                            // 128 MB  [16384,2048] fp32
    float* Wxcat = ws + (size_t)33554432;         //   8 MB  [2048,1024] fp32
    float* Weff  = ws + (size_t)35651584;         //   8 MB  [2048,1024] fp32
    char*  wsplit= (char*)Wxcat;                  //   8 MB  overwrites Wxcat after use

    float* out_  = (float*)d_out;                 // [T,B,512]
    float* Sfin  = out_ + (size_t)TT * BB * HN;   // [B,H,N,N]

    concat4<<<dim3(2048), dim3(256), 0, stream>>>(W_k, W_v, W_q, W_beta, Wxcat);
    gemm_f32<<<dim3(DD/128, FF/128), dim3(256), 0, stream>>>(Wxcat, W_in, Weff, FF, DD, DD);
    wconv<<<dim3(512), dim3(256), 0, stream>>>(Weff, wsplit);
    gemm_mfma<<<dim3(2048), dim3(256), 0, stream>>>(x, wsplit, proj, b_beta);
    recur<<<dim3(512), dim3(128), 0, stream>>>(proj, S0, out_, Sfin);
}

// Round 6
// 603.218 us; speedup vs baseline: 1.4298x; 1.4298x over previous
//
#include <hip/hip_runtime.h>
#include <hip/hip_bf16.h>
#include <stdint.h>

#define TT 2048
#define BB 8
#define DD 1024
#define FF 2048   // 4*H*N
#define HN 512
#define KB_CNT 32         // DD/32 k-blocks
#define ROWB 128          // bytes per (row, k-block): 8 slots * 16B
#define MSTRIDE 4096      // bytes per row in split layout = KB_CNT*ROWB
#define PF 8              // recurrence pipeline depth (8 steps * 4 loads = 32 in flight)

typedef float f32x4 __attribute__((ext_vector_type(4)));
typedef float f32x2 __attribute__((ext_vector_type(2)));
typedef _Float16 h8_t __attribute__((ext_vector_type(8)));

// ---------- fast math helpers ----------
__device__ __forceinline__ float fexp2(float x){ return __builtin_amdgcn_exp2f(x); }
__device__ __forceinline__ float frcp(float x){ return __builtin_amdgcn_rcpf(x); }
__device__ __forceinline__ float fsqrt_(float x){ return __builtin_amdgcn_sqrtf(x); }
__device__ __forceinline__ float fast_sigmoid(float x){
    return frcp(1.0f + fexp2(-1.44269504f * x));
}

// DPP butterfly add (old=0, bound_ctrl; fetches confined to 16-lane DPP row)
template<int CTRL>
__device__ __forceinline__ float dppadd(float v){
    int x = __builtin_amdgcn_update_dpp(0, __float_as_int(v), CTRL, 0xf, 0xf, true);
    return v + __int_as_float(x);
}
// sum over 16-lane group
__device__ __forceinline__ float reduce16(float v){
    v = dppadd<0xB1>(v);   // + lane^1
    v = dppadd<0x4E>(v);   // + lane^2
    v = dppadd<0x141>(v);  // row_half_mirror: + lane^4
    v = dppadd<0x140>(v);  // row_mirror:      + lane^8
    return v;
}

// ---------- concat the 4 projection weights into [2048,1024] ----------
__global__ __launch_bounds__(256)
void concat4(const float* __restrict__ s0, const float* __restrict__ s1,
             const float* __restrict__ s2, const float* __restrict__ s3,
             float* __restrict__ dst)
{
    size_t i = (size_t)blockIdx.x * 256 + threadIdx.x;
    const size_t q = (size_t)HN * DD / 4;
    const float* s = (i < q) ? s0 : (i < 2*q) ? s1 : (i < 3*q) ? s2 : s3;
    size_t off = i & (q - 1);
    ((float4*)dst)[i] = ((const float4*)s)[off];
}

// ---------- fp32 tiled GEMM (only for the tiny Weff product) ----------
__global__ __launch_bounds__(256)
void gemm_f32(const float* __restrict__ A, const float* __restrict__ B,
              float* __restrict__ C, int M, int N, int K)
{
    __shared__ __align__(16) float As[16][132];
    __shared__ __align__(16) float Bs[16][144];
    const int tid = threadIdx.x;
    const int tx = tid & 15, ty = tid >> 4;
    const int n0 = blockIdx.x * 128, m0 = blockIdx.y * 128;
    float acc[8][8] = {};
    for (int k0 = 0; k0 < K; k0 += 16) {
        #pragma unroll
        for (int rr = 0; rr < 2; ++rr) {
            int idx = tid + rr * 256;
            int row = idx >> 2, c4 = (idx & 3) << 2;
            float4 v = *(const float4*)&A[(size_t)(m0 + row) * K + k0 + c4];
            As[c4+0][row] = v.x; As[c4+1][row] = v.y;
            As[c4+2][row] = v.z; As[c4+3][row] = v.w;
        }
        #pragma unroll
        for (int rr = 0; rr < 2; ++rr) {
            int idx = tid + rr * 256;
            int kk = idx >> 5, c = idx & 31;
            float4 v = *(const float4*)&B[(size_t)(k0 + kk) * N + n0 + (c << 2)];
            int p = c + (c >> 3);
            *(float4*)&Bs[kk][p << 2] = v;
        }
        __syncthreads();
        #pragma unroll
        for (int kk = 0; kk < 16; ++kk) {
            float a[8], b[8];
            *(float4*)&a[0] = *(const float4*)&As[kk][ty * 8];
            *(float4*)&a[4] = *(const float4*)&As[kk][ty * 8 + 4];
            int c = tx * 2, p = c + (c >> 3);
            *(float4*)&b[0] = *(const float4*)&Bs[kk][p << 2];
            *(float4*)&b[4] = *(const float4*)&Bs[kk][(p + 1) << 2];
            #pragma unroll
            for (int i = 0; i < 8; ++i)
                #pragma unroll
                for (int j = 0; j < 8; ++j)
                    acc[i][j] += a[i] * b[j];
        }
        __syncthreads();
    }
    #pragma unroll
    for (int ii = 0; ii < 8; ++ii) {
        int m = m0 + ty * 8 + ii;
        float* crow = &C[(size_t)m * N + n0 + tx * 8];
        #pragma unroll
        for (int jj = 0; jj < 2; ++jj) {
            float4 v;
            v.x = acc[ii][jj*4+0]; v.y = acc[ii][jj*4+1];
            v.z = acc[ii][jj*4+2]; v.w = acc[ii][jj*4+3];
            *(float4*)&crow[jj * 4] = v;
        }
    }
}

// ---------- split fp32 -> (hi,lo) fp16, pre-swizzled layout ----------
__device__ __forceinline__ void split8(const float* f, int4& hi, int4& lo){
    union { _Float16 h[8]; int4 i; } a, c;
    #pragma unroll
    for (int u = 0; u < 8; ++u) {
        _Float16 h = (_Float16)f[u];
        a.h[u] = h;
        c.h[u] = (_Float16)(f[u] - (float)h);
    }
    hi = a.i; lo = c.i;
}

__global__ __launch_bounds__(256)
void wconv(const float* __restrict__ W, char* __restrict__ out)
{
    int gid = blockIdx.x * 256 + threadIdx.x;
    int n  = gid >> 6;
    int kh = gid & 63;
    const float* src = W + (size_t)n * DD + kh * 16;
    float f[16];
    *(float4*)&f[0]  = *(const float4*)(src + 0);
    *(float4*)&f[4]  = *(const float4*)(src + 4);
    *(float4*)&f[8]  = *(const float4*)(src + 8);
    *(float4*)&f[12] = *(const float4*)(src + 12);
    int4 hi0, hi1, lo0, lo1;
    split8(&f[0], hi0, lo0);
    split8(&f[8], hi1, lo1);
    int kb = kh >> 1, c0 = (kh & 1) * 2, rs = n & 7;
    char* dst = out + (size_t)n * MSTRIDE + kb * ROWB;
    *(int4*)(dst + (((c0+0) ^ rs) * 16)) = hi0;
    *(int4*)(dst + (((c0+1) ^ rs) * 16)) = hi1;
    *(int4*)(dst + (((c0+4) ^ rs) * 16)) = lo0;
    *(int4*)(dst + (((c0+5) ^ rs) * 16)) = lo1;
}

// ---------- fp16x2-split MFMA GEMM ----------
// nt<4 (k block): epilogue normalizes each row's 32-col h-group in-register
// (reduce16 over the fl lanes aligns exactly with the C/D 16-lane DPP rows).
// nt>=12 (beta block): sigmoid(+bias).
__global__ __launch_bounds__(256)
void gemm_mfma(const float* __restrict__ A, const char* __restrict__ Wsp,
               float* __restrict__ C, const float* __restrict__ bias)
{
    __shared__ char lds[32768];
    char* Asb = lds;
    char* Bsb = lds + 16384;

    const int tid  = threadIdx.x;
    const int wave = tid >> 6, lane = tid & 63;
    const int wm = wave >> 1, wn = wave & 1;
    const int nt = blockIdx.x & 15, mt = blockIdx.x >> 4;
    const int m0 = mt * 128, n0 = nt * 128;

    f32x4 acc[4][4] = {};

    const int ar = tid >> 1, akh = tid & 1, ars = ar & 7, ac0 = akh * 2;
    const float* asrc = A + (size_t)(m0 + ar) * DD + akh * 16;
    char* awr = Asb + ar * ROWB;

    const char* bsrc_base = Wsp + (size_t)n0 * MSTRIDE;

    const int fl = lane & 15, fh = lane >> 4;
    const int shi = (fh ^ (fl & 7)) * 16;
    const int slo = ((fh + 4) ^ (fl & 7)) * 16;
    const int frow = fl * ROWB;

    for (int ks = 0; ks < KB_CNT; ++ks) {
        #pragma unroll
        for (int gg = 0; gg < 4; ++gg) {
            int g = wave * 4 + gg;
            const char* src = bsrc_base + (size_t)(g * 8 + (lane >> 3)) * MSTRIDE
                              + ks * ROWB + (lane & 7) * 16;
            __builtin_amdgcn_global_load_lds(
                (const __attribute__((address_space(1))) uint32_t*)src,
                (__attribute__((address_space(3))) uint32_t*)(Bsb + g * 1024),
                16, 0, 0);
        }
        {
            const float* ap = asrc + ks * 32;
            float f[16];
            *(float4*)&f[0]  = *(const float4*)(ap + 0);
            *(float4*)&f[4]  = *(const float4*)(ap + 4);
            *(float4*)&f[8]  = *(const float4*)(ap + 8);
            *(float4*)&f[12] = *(const float4*)(ap + 12);
            int4 hi0, hi1, lo0, lo1;
            split8(&f[0], hi0, lo0);
            split8(&f[8], hi1, lo1);
            *(int4*)(awr + (((ac0+0) ^ ars) * 16)) = hi0;
            *(int4*)(awr + (((ac0+1) ^ ars) * 16)) = hi1;
            *(int4*)(awr + (((ac0+4) ^ ars) * 16)) = lo0;
            *(int4*)(awr + (((ac0+5) ^ ars) * 16)) = lo1;
        }
        __syncthreads();

        union { int4 i; h8_t h; } ah[4], al[4], bh[4], bl[4];
        #pragma unroll
        for (int fm = 0; fm < 4; ++fm) {
            const char* base = Asb + (wm * 64 + fm * 16) * ROWB + frow;
            ah[fm].i = *(const int4*)(base + shi);
            al[fm].i = *(const int4*)(base + slo);
        }
        #pragma unroll
        for (int fn = 0; fn < 4; ++fn) {
            const char* base = Bsb + (wn * 64 + fn * 16) * ROWB + frow;
            bh[fn].i = *(const int4*)(base + shi);
            bl[fn].i = *(const int4*)(base + slo);
        }
        #pragma unroll
        for (int fm = 0; fm < 4; ++fm)
            #pragma unroll
            for (int fn = 0; fn < 4; ++fn) {
                acc[fm][fn] = __builtin_amdgcn_mfma_f32_16x16x32_f16(ah[fm].h, bh[fn].h, acc[fm][fn], 0, 0, 0);
                acc[fm][fn] = __builtin_amdgcn_mfma_f32_16x16x32_f16(ah[fm].h, bl[fn].h, acc[fm][fn], 0, 0, 0);
                acc[fm][fn] = __builtin_amdgcn_mfma_f32_16x16x32_f16(al[fm].h, bh[fn].h, acc[fm][fn], 0, 0, 0);
            }
        __syncthreads();
    }

    if (nt < 4) {
        // normalize k rows: each 32-col h-group = fn pair (2hg, 2hg+1) x 16 fl lanes
        #pragma unroll
        for (int fm = 0; fm < 4; ++fm)
            #pragma unroll
            for (int hg = 0; hg < 2; ++hg)
                #pragma unroll
                for (int reg = 0; reg < 4; ++reg) {
                    float a = acc[fm][hg*2][reg], c = acc[fm][hg*2+1][reg];
                    float p = __builtin_fmaf(a, a, c * c);
                    p = reduce16(p);
                    float rn = frcp(fsqrt_(p) + 1e-6f);
                    acc[fm][hg*2][reg]   = a * rn;
                    acc[fm][hg*2+1][reg] = c * rn;
                }
    }

    const bool isbeta = (nt >= 12);
    #pragma unroll
    for (int fm = 0; fm < 4; ++fm) {
        int rbase = m0 + wm * 64 + fm * 16 + fh * 4;
        #pragma unroll
        for (int fn = 0; fn < 4; ++fn) {
            int col = n0 + wn * 64 + fn * 16 + fl;
            float bb = isbeta ? bias[col - 3 * HN] : 0.0f;
            #pragma unroll
            for (int reg = 0; reg < 4; ++reg) {
                float v = acc[fm][fn][reg];
                if (isbeta) v = fast_sigmoid(v + bb);
                C[(size_t)(rbase + reg) * FF + col] = v;
            }
        }
    }
}

// ---------- sequential recurrence ----------
// 256 blocks x 256 threads (4 waves = 1 wave/SIMD on all SIMDs; 2 blocks/chain
// like R3 -> duplicated k/q reads stay L2-absorbed). 16 lanes/row, 2 j/thread.
// k is pre-normalized by gemm_mfma. Carried chain per step:
// fma(dot) -> 4 DPP -> fma(d) -> fma(arg) -> exp2 -> add -> rcp -> fma.
// Output stores batched 8-per-block so they leave the per-step vmcnt window.
__global__ __launch_bounds__(256)
void recur(const float* __restrict__ proj, const float* __restrict__ S0,
           float* __restrict__ out, float* __restrict__ Sfin)
{
    const int tid = threadIdx.x;
    const int bx  = blockIdx.x;
    const int bh  = bx >> 1;                       // chain 0..127
    const int b   = bh >> 4, h = bh & 15;
    const int i   = ((bx & 1) << 4) + (tid >> 4);  // state row 0..31
    const int jl  = tid & 15;                      // owns j = 2jl, 2jl+1

    float S0v, S1v;
    {
        const float* s0p = S0 + (size_t)bh * 1024 + i * 32 + 2 * jl;
        S0v = s0p[0]; S1v = s0p[1];
    }

    const size_t rowstep = (size_t)BB * FF;        // 16384 floats per t
    const float* pk = proj + (size_t)b * FF + h * 32 + 2 * jl;      // normalized k
    const float* pq = pk + 2 * HN;
    const float* pv = proj + (size_t)b * FF + HN + h * 32 + i;
    const float* pb = pv + 2 * HN;

    f32x2 K[PF], Q[PF];
    float V[PF], Bt[PF];

    // prologue: issue PF steps (4 loads each, order k,q,v,b); advance pointers
    #pragma unroll
    for (int p = 0; p < PF; ++p) {
        asm volatile("global_load_dwordx2 %0, %1, off" : "=v"(K[p])  : "v"(pk));
        asm volatile("global_load_dwordx2 %0, %1, off" : "=v"(Q[p])  : "v"(pq));
        asm volatile("global_load_dword %0, %1, off"   : "=v"(V[p])  : "v"(pv));
        asm volatile("global_load_dword %0, %1, off"   : "=v"(Bt[p]) : "v"(pb));
        pk += rowstep; pq += rowstep; pv += rowstep; pb += rowstep;
    }

    // prime step-0 off-chain constants (wait slot 0: 32 -> 28 outstanding)
    asm volatile("s_waitcnt vmcnt(28)"
        : "+v"(K[0]), "+v"(Q[0]), "+v"(V[0]), "+v"(Bt[0]));
    const float Cc = 2.88539008f;   // 2/ln2
    float cv_cur = Cc * V[0];
    float b2 = Cc * Bt[0];
    float bS0 = b2 * S0v, bS1 = b2 * S1v;

    float* pout = out + (size_t)b * HN + h * 32 + i;   // stored when jl==0

    for (int t0 = 0; t0 < TT; t0 += PF) {
        float osave[PF];
        #pragma unroll
        for (int p = 0; p < PF; ++p) {
            const int pn = (p + 1) & (PF - 1);
            // drains slot pn (next step); data-threading orders consumers.
            asm volatile("s_waitcnt vmcnt(24)"
                : "+v"(K[pn]), "+v"(Q[pn]), "+v"(V[pn]), "+v"(Bt[pn]));

            // ---- carried chain (k pre-normalized) ----
            f32x2 k2 = K[p];
            float rr = S0v * k2[0];
            rr = __builtin_fmaf(S1v, k2[1], rr);
            rr = reduce16(rr);
            float d  = __builtin_fmaf(-Cc, rr, cv_cur);   // C*(v - S.kn)
            float a0 = __builtin_fmaf(d, k2[0], bS0);
            float a1 = __builtin_fmaf(d, k2[1], bS1);
            float r0 = frcp(fexp2(a0) + 1.0f);
            float r1 = frcp(fexp2(a1) + 1.0f);
            S0v = __builtin_fmaf(-2.0f, r0, 1.0f);
            S1v = __builtin_fmaf(-2.0f, r1, 1.0f);

            // ---- output (raw Sq; finished + stored in batch below) ----
            f32x2 q2 = Q[p];
            float sq = S0v * q2[0];
            sq = __builtin_fmaf(S1v, q2[1], sq);
            osave[p] = reduce16(sq);

            // ---- off-chain constants for step t+1 ----
            cv_cur = Cc * V[pn];
            b2 = Cc * Bt[pn];
            bS0 = b2 * S0v; bS1 = b2 * S1v;

            // ---- reissue slot p for step t+PF ----
            // (tail overrun lands in the dead wsplit region of ws; never consumed)
            asm volatile("global_load_dwordx2 %0, %1, off" : "=v"(K[p])  : "v"(pk));
            asm volatile("global_load_dwordx2 %0, %1, off" : "=v"(Q[p])  : "v"(pq));
            asm volatile("global_load_dword %0, %1, off"   : "=v"(V[p])  : "v"(pv));
            asm volatile("global_load_dword %0, %1, off"   : "=v"(Bt[p]) : "v"(pb));
            pk += rowstep; pq += rowstep; pv += rowstep; pb += rowstep;
        }
        // ---- batched stores (leave the per-step vmcnt window) ----
        if (jl == 0) {
            #pragma unroll
            for (int p = 0; p < PF; ++p) {
                float sq = osave[p];
                float sg = fast_sigmoid(sq);
                pout[(size_t)p * (BB * HN)] = sq * sq * sg;
            }
        }
        pout += (size_t)PF * (BB * HN);
    }

    {
        float* sf = Sfin + (size_t)bh * 1024 + i * 32 + 2 * jl;
        sf[0] = S0v; sf[1] = S1v;
    }
}

extern "C" void kernel_launch(void* const* d_in, const int* in_sizes, int n_in,
                              void* d_out, int out_size, void* d_ws, size_t ws_size,
                              hipStream_t stream) {
    const float* x      = (const float*)d_in[0];
    const float* S0     = (const float*)d_in[1];
    const float* W_in   = (const float*)d_in[2];
    const float* W_k    = (const float*)d_in[3];
    const float* W_v    = (const float*)d_in[4];
    const float* W_q    = (const float*)d_in[5];
    const float* W_beta = (const float*)d_in[6];
    const float* b_beta = (const float*)d_in[7];

    float* ws    = (float*)d_ws;
    float* proj  = ws;                            // 128 MB  [16384,2048] fp32
    float* Wxcat = ws + (size_t)33554432;         //   8 MB  [2048,1024] fp32
    float* Weff  = ws + (size_t)35651584;         //   8 MB  [2048,1024] fp32
    char*  wsplit= (char*)Wxcat;                  //   8 MB  overwrites Wxcat after use

    float* out_  = (float*)d_out;                 // [T,B,512]
    float* Sfin  = out_ + (size_t)TT * BB * HN;   // [B,H,N,N]

    concat4<<<dim3(2048), dim3(256), 0, stream>>>(W_k, W_v, W_q, W_beta, Wxcat);
    gemm_f32<<<dim3(DD/128, FF/128), dim3(256), 0, stream>>>(Wxcat, W_in, Weff, FF, DD, DD);
    wconv<<<dim3(512), dim3(256), 0, stream>>>(Weff, wsplit);
    gemm_mfma<<<dim3(2048), dim3(256), 0, stream>>>(x, wsplit, proj, b_beta);
    recur<<<dim3(256), dim3(256), 0, stream>>>(proj, S0, out_, Sfin);
}